// Round 6
// baseline (5310.043 us; speedup 1.0000x reference)
//
#include <hip/hip_runtime.h>
#include <hip/hip_fp16.h>
#include <cstdint>
#include <cstddef>

typedef _Float16 half_t;
typedef _Float16 half2_t __attribute__((ext_vector_type(2)));
typedef _Float16 half8_t __attribute__((ext_vector_type(8)));
typedef float    f32x4   __attribute__((ext_vector_type(4)));
typedef unsigned int uint4v __attribute__((ext_vector_type(4)));

#define T_FULL  2048
#define T_CH    512
#define N_CHUNK 4
#define B_SZ    64
#define H_SZ    256
#define G4      1024
#define CH_M    (B_SZ * T_CH)   // 32768

// ---------------- workspace layout (bytes) ----------------
static constexpr size_t OFF_XW   = 0;                                   // half [CH_M][1024] (i,f,g,o)x256
static constexpr size_t OFF_H    = OFF_XW   + (size_t)CH_M * G4 * 2;    // half [CH_M][256]
static constexpr size_t OFF_WIH  = OFF_H    + (size_t)CH_M * H_SZ * 2;  // half [1024][256]  (B^T)
static constexpr size_t OFF_WOUT = OFF_WIH  + (size_t)G4 * 256 * 2;     // half [256][256]   (B^T)
static constexpr size_t OFF_WMF  = OFF_WOUT + (size_t)256 * 256 * 2;    // uint4 frag[8][64][64]  (MFMA B-frags)
static constexpr size_t OFF_SC   = OFF_WMF  + (size_t)8 * 64 * 64 * 16; // float [64][256]
static constexpr size_t OFF_SH   = OFF_SC   + (size_t)B_SZ * H_SZ * 4;  // uint [64][128] f16 pairs

// ---------------- helpers ----------------
__device__ __forceinline__ unsigned int packh2(float a, float b) {
    half2_t h; h.x = (half_t)a; h.y = (half_t)b;
    return __builtin_bit_cast(unsigned int, h);
}

__device__ __forceinline__ float sigm(float x)  { return 1.0f / (1.0f + __expf(-x)); }
__device__ __forceinline__ float tanh_(float x) { return 1.0f - 2.0f / (__expf(2.0f * x) + 1.0f); }

// ---------------- K0: pack weights + init state ----------------
// word sections: wih 262144 | wout 65536 | mf 131072 | c 16384 | h 8192
static constexpr int PACK_TOTAL = 262144 + 65536 + 131072 + 16384 + 8192;

__global__ __launch_bounds__(256) void pack_kernel(
    const float* __restrict__ Wih, const float* __restrict__ Whh,
    const float* __restrict__ Wout, const float* __restrict__ c0,
    const float* __restrict__ h0,
    half_t* __restrict__ wih_t, half_t* __restrict__ wout_t,
    unsigned int* __restrict__ whh_mf,
    float* __restrict__ state_c, unsigned int* __restrict__ state_h)
{
    const int stride = gridDim.x * blockDim.x;
    for (int idx = blockIdx.x * blockDim.x + threadIdx.x; idx < PACK_TOTAL; idx += stride) {
        int r = idx;
        if (r < 262144) {                       // wih_t[n][k] = Wih[k][n]
            int n = r >> 8, k = r & 255;
            wih_t[r] = (half_t)Wih[k * 1024 + n];
            continue;
        }
        r -= 262144;
        if (r < 65536) {                        // wout_t[n][k] = Wout[k][n]
            int n = r >> 8, k = r & 255;
            wout_t[r] = (half_t)Wout[k * 256 + n];
            continue;
        }
        r -= 65536;
        if (r < 131072) {                       // MFMA B-frags: frag[kt][nt][lane], 4 words each
            int j    = r & 3;                   // word within frag (k pair 2j,2j+1)
            int lane = (r >> 2) & 63;
            int nt   = (r >> 8) & 63;
            int kt   = r >> 14;
            int k0 = kt * 32 + ((lane >> 4) << 3) + 2 * j;
            int n  = nt * 16 + (lane & 15);
            whh_mf[r] = packh2(Whh[k0 * 1024 + n], Whh[(k0 + 1) * 1024 + n]);
            continue;
        }
        r -= 131072;
        if (r < 16384) { state_c[r] = c0[r]; continue; }
        r -= 16384;
        state_h[r] = packh2(h0[2 * r], h0[2 * r + 1]);
    }
}

// ---------------- K1/K3: f16 MFMA GEMM, 128x128 tile, K=256 ----------------
template<int AMODE, int CMODE>
__global__ __launch_bounds__(256) void gemm16(
    const void* __restrict__ Ap, const half_t* __restrict__ Bt,
    void* __restrict__ Cp, const float* __restrict__ bias, int chunk0)
{
    __shared__ half_t Als[128][40];
    __shared__ half_t Bls[128][40];
    const int tid  = threadIdx.x;
    const int lane = tid & 63, wid = tid >> 6;
    const int wr = wid >> 1, wc = wid & 1;
    const int m0 = blockIdx.x * 128, n0 = blockIdx.y * 128;

    f32x4 acc[4][4] = {};

    for (int kc = 0; kc < 8; ++kc) {
        __syncthreads();
        if (AMODE == 1) {
            const float* A = (const float*)Ap;
            #pragma unroll
            for (int i = 0; i < 4; ++i) {
                int l = tid + i * 256;
                int row = l >> 3, kq = l & 7;
                int m = m0 + row;
                int arow = ((m >> 9) << 11) + chunk0 + (m & 511);
                f32x4 v = *(const f32x4*)(A + (size_t)arow * 256 + kc * 32 + kq * 4);
                uint2 pk;
                pk.x = packh2(v.x, v.y);
                pk.y = packh2(v.z, v.w);
                *reinterpret_cast<uint2*>(&Als[row][kq * 4]) = pk;
            }
        } else {
            const half_t* A = (const half_t*)Ap;
            #pragma unroll
            for (int i = 0; i < 2; ++i) {
                int l = tid + i * 256;
                int row = l >> 2, ko = l & 3;
                half8_t v = *(const half8_t*)(A + (size_t)(m0 + row) * 256 + kc * 32 + ko * 8);
                *reinterpret_cast<half8_t*>(&Als[row][ko * 8]) = v;
            }
        }
        #pragma unroll
        for (int i = 0; i < 2; ++i) {
            int l = tid + i * 256;
            int row = l >> 2, ko = l & 3;
            half8_t v = *(const half8_t*)(Bt + (size_t)(n0 + row) * 256 + kc * 32 + ko * 8);
            *reinterpret_cast<half8_t*>(&Bls[row][ko * 8]) = v;
        }
        __syncthreads();

        half8_t af[4], bf[4];
        #pragma unroll
        for (int mi = 0; mi < 4; ++mi)
            af[mi] = *reinterpret_cast<const half8_t*>(&Als[wr * 64 + mi * 16 + (lane & 15)][(lane >> 4) * 8]);
        #pragma unroll
        for (int ni = 0; ni < 4; ++ni)
            bf[ni] = *reinterpret_cast<const half8_t*>(&Bls[wc * 64 + ni * 16 + (lane & 15)][(lane >> 4) * 8]);
        #pragma unroll
        for (int mi = 0; mi < 4; ++mi)
            #pragma unroll
            for (int ni = 0; ni < 4; ++ni)
                acc[mi][ni] = __builtin_amdgcn_mfma_f32_16x16x32_f16(af[mi], bf[ni], acc[mi][ni], 0, 0, 0);
    }

    #pragma unroll
    for (int mi = 0; mi < 4; ++mi) {
        #pragma unroll
        for (int ni = 0; ni < 4; ++ni) {
            #pragma unroll
            for (int reg = 0; reg < 4; ++reg) {
                int row = m0 + wr * 64 + mi * 16 + (lane >> 4) * 4 + reg;   // m
                int col = n0 + wc * 64 + ni * 16 + (lane & 15);             // n
                float v = acc[mi][ni][reg] + bias[col];
                if (CMODE == 0) {
                    ((half_t*)Cp)[(size_t)row * 1024 + ((col & 255) << 2) + (col >> 8)] = (half_t)v;
                } else {
                    int crow = ((row >> 9) << 11) + chunk0 + (row & 511);
                    ((float*)Cp)[(size_t)crow * 256 + col] = v;
                }
            }
        }
    }
}

// ---------------- K2: per-chain recurrent LSTM via MFMA (M=1) ----------------
// 64 blocks (one chain each), 256 threads = 4 waves = 1 wave/SIMD -> 512-reg
// unified budget per wave (waves_per_eu(1,1)). Wave w owns N-tiles w*16..w*16+15.
// B-frags: kt 0..5 register/AGPR-resident (384 regs), kt 6..7 in LDS (128 KB).
// Zero per-step global B traffic; per-step cost ~ max(MFMA issue 640, LDS 1024 cyc).
__global__
__attribute__((amdgpu_flat_work_group_size(256, 256), amdgpu_waves_per_eu(1, 1)))
void rnn_kernel(
    const uint4v* __restrict__ whh_mf,
    const half_t* __restrict__ xw,
    half_t* __restrict__ h_out,
    float* __restrict__ state_c,
    unsigned int* __restrict__ state_h)
{
    __shared__ uint4v lds_b[2 * 4096];       // B-frags kt 6,7: 131072 B
    __shared__ float  gbuf[1024];            // 4096 B
    __shared__ unsigned int hbuf[128];       // 512 B = h as 256 f16

    const int t    = threadIdx.x;
    const int lane = t & 63;
    const int w    = t >> 6;                 // wave 0..3
    const int b    = blockIdx.x;

    for (int i = t; i < 8192; i += 256) lds_b[i] = whh_mf[6 * 4096 + i];
    if (t < 128) hbuf[t] = state_h[b * 128 + t];
    float c = state_c[b * 256 + t];

    // resident B-frags: kt 0..5, this wave's 16 N-tiles (384 regs -> VGPR+AGPR)
    const half8_t* mf8 = (const half8_t*)whh_mf;
    half8_t Bres[6][16];
    #pragma unroll
    for (int kt = 0; kt < 6; ++kt)
        #pragma unroll
        for (int n = 0; n < 16; ++n)
            Bres[kt][n] = mf8[((size_t)kt * 64 + w * 16 + n) * 64 + lane];
    __syncthreads();

    const half_t* xwp = xw + (size_t)b * T_CH * 1024 + t * 4;
    half_t* hop = h_out + (size_t)b * T_CH * 256 + t;
    const half_t* hbh = (const half_t*)hbuf;

    #pragma unroll 1
    for (int step = 0; step < T_CH; ++step) {
        uint2 xv = *(const uint2*)xwp;

        // A-frags: row 0 = h (lanes with lane&15==0 carry k-chunks), rows 1-15 zero
        half8_t a[8];
        #pragma unroll
        for (int kt = 0; kt < 8; ++kt) {
            half8_t v = {};
            if ((lane & 15) == 0)
                v = *(const half8_t*)(hbh + kt * 32 + (lane >> 4) * 8);
            a[kt] = v;
        }

        // 16 N-tiles in 4 clusters of 4 (caps transient regs at ~48)
        #pragma unroll
        for (int cl = 0; cl < 4; ++cl) {
            const int nb = w * 16 + cl * 4;
            half8_t l6[4], l7[4];
            #pragma unroll
            for (int i = 0; i < 4; ++i) {
                l6[i] = *(const half8_t*)&lds_b[0 * 4096 + (size_t)(nb + i) * 64 + lane];
                l7[i] = *(const half8_t*)&lds_b[1 * 4096 + (size_t)(nb + i) * 64 + lane];
            }
            #pragma unroll
            for (int i = 0; i < 4; ++i) {
                const int ni = cl * 4 + i;
                f32x4 cc = {};
                cc = __builtin_amdgcn_mfma_f32_16x16x32_f16(a[0], Bres[0][ni], cc, 0, 0, 0);
                cc = __builtin_amdgcn_mfma_f32_16x16x32_f16(a[1], Bres[1][ni], cc, 0, 0, 0);
                cc = __builtin_amdgcn_mfma_f32_16x16x32_f16(a[2], Bres[2][ni], cc, 0, 0, 0);
                cc = __builtin_amdgcn_mfma_f32_16x16x32_f16(a[3], Bres[3][ni], cc, 0, 0, 0);
                cc = __builtin_amdgcn_mfma_f32_16x16x32_f16(a[4], Bres[4][ni], cc, 0, 0, 0);
                cc = __builtin_amdgcn_mfma_f32_16x16x32_f16(a[5], Bres[5][ni], cc, 0, 0, 0);
                cc = __builtin_amdgcn_mfma_f32_16x16x32_f16(a[6], l6[i], cc, 0, 0, 0);
                cc = __builtin_amdgcn_mfma_f32_16x16x32_f16(a[7], l7[i], cc, 0, 0, 0);
                // C row 0 lives in lanes 0-15, reg 0
                if (lane < 16) gbuf[(nb + i) * 16 + lane] = cc[0];
            }
        }
        __syncthreads();   // gbuf writes -> update reads; hbuf reads -> update write

        // update phase: all 256 threads, element e = t
        {
            half2_t x0 = __builtin_bit_cast(half2_t, xv.x);
            half2_t x1 = __builtin_bit_cast(half2_t, xv.y);
            float a0 = gbuf[t]       + (float)x0.x;
            float a1 = gbuf[256 + t] + (float)x0.y;
            float a2 = gbuf[512 + t] + (float)x1.x;
            float a3 = gbuf[768 + t] + (float)x1.y;
            float ig = sigm(a0), fg = sigm(a1), gg = tanh_(a2), og = sigm(a3);
            c = fg * c + ig * gg;
            float hn = og * tanh_(c);
            half_t h16 = (half_t)hn;
            ((half_t*)hbuf)[t] = h16;
            xwp += 1024;
            __syncthreads();   // hbuf write -> next A-read; gbuf read -> next write

            // deferred global store: drains at NEXT step's barrier, off the critical path
            *hop = h16;
            hop += 256;
        }
    }

    state_c[b * 256 + t] = c;
    if (t < 128) state_h[b * 128 + t] = hbuf[t];
}

// ---------------- launch ----------------
extern "C" void kernel_launch(void* const* d_in, const int* in_sizes, int n_in,
                              void* d_out, int out_size, void* d_ws, size_t ws_size,
                              hipStream_t stream) {
    const float* x    = (const float*)d_in[0];
    const float* c0   = (const float*)d_in[1];
    const float* h0   = (const float*)d_in[2];
    const float* Wih  = (const float*)d_in[3];
    const float* Whh  = (const float*)d_in[4];
    const float* bh   = (const float*)d_in[5];
    const float* Wout = (const float*)d_in[6];
    const float* bout = (const float*)d_in[7];

    char* ws = (char*)d_ws;
    half_t* xw             = (half_t*)(ws + OFF_XW);
    half_t* h_chunk        = (half_t*)(ws + OFF_H);
    half_t* wih_t          = (half_t*)(ws + OFF_WIH);
    half_t* wout_t         = (half_t*)(ws + OFF_WOUT);
    unsigned int* whh_mf   = (unsigned int*)(ws + OFF_WMF);
    float* state_c         = (float*)(ws + OFF_SC);
    unsigned int* state_h  = (unsigned int*)(ws + OFF_SH);

    pack_kernel<<<512, 256, 0, stream>>>(Wih, Whh, Wout, c0, h0,
                                         wih_t, wout_t, whh_mf,
                                         state_c, state_h);

    for (int ch = 0; ch < N_CHUNK; ++ch) {
        int chunk0 = ch * T_CH;
        gemm16<1, 0><<<dim3(CH_M / 128, G4 / 128), 256, 0, stream>>>(
            (const void*)x, wih_t, (void*)xw, bh, chunk0);
        rnn_kernel<<<B_SZ, 256, 0, stream>>>((const uint4v*)(ws + OFF_WMF),
                                             xw, h_chunk, state_c, state_h);
        gemm16<0, 1><<<dim3(CH_M / 128, H_SZ / 128), 256, 0, stream>>>(
            (const void*)h_chunk, wout_t, d_out, bout, chunk0);
    }
    (void)in_sizes; (void)n_in; (void)out_size; (void)ws_size;
}

// Round 7
// 5136.102 us; speedup vs baseline: 1.0339x; 1.0339x over previous
//
#include <hip/hip_runtime.h>
#include <hip/hip_fp16.h>
#include <cstdint>
#include <cstddef>

typedef _Float16 half_t;
typedef _Float16 half2_t __attribute__((ext_vector_type(2)));
typedef _Float16 half8_t __attribute__((ext_vector_type(8)));
typedef float    f32x4   __attribute__((ext_vector_type(4)));
typedef unsigned int uint4v __attribute__((ext_vector_type(4)));

#define T_FULL  2048
#define T_CH    512
#define N_CHUNK 4
#define B_SZ    64
#define H_SZ    256
#define G4      1024
#define CH_M    (B_SZ * T_CH)   // 32768

// ---------------- workspace layout (bytes) ----------------
static constexpr size_t OFF_XW   = 0;                                   // half [CH_M][1024] (i,f,g,o)x256
static constexpr size_t OFF_H    = OFF_XW   + (size_t)CH_M * G4 * 2;    // half [CH_M][256]
static constexpr size_t OFF_WIH  = OFF_H    + (size_t)CH_M * H_SZ * 2;  // half [1024][256]  (B^T)
static constexpr size_t OFF_WOUT = OFF_WIH  + (size_t)G4 * 256 * 2;     // half [256][256]   (B^T)
static constexpr size_t OFF_WMF  = OFF_WOUT + (size_t)256 * 256 * 2;    // uint4 frag[8][64][64]  (MFMA B-frags)
static constexpr size_t OFF_SC   = OFF_WMF  + (size_t)8 * 64 * 64 * 16; // float [64][256]
static constexpr size_t OFF_SH   = OFF_SC   + (size_t)B_SZ * H_SZ * 4;  // uint [64][128] f16 pairs

// ---------------- helpers ----------------
__device__ __forceinline__ unsigned int packh2(float a, float b) {
    half2_t h; h.x = (half_t)a; h.y = (half_t)b;
    return __builtin_bit_cast(unsigned int, h);
}

__device__ __forceinline__ float sigm(float x)  { return 1.0f / (1.0f + __expf(-x)); }
__device__ __forceinline__ float tanh_(float x) { return 1.0f - 2.0f / (__expf(2.0f * x) + 1.0f); }

// ---------------- K0: pack weights + init state ----------------
// word sections: wih 262144 | wout 65536 | mf 131072 | c 16384 | h 8192
static constexpr int PACK_TOTAL = 262144 + 65536 + 131072 + 16384 + 8192;

__global__ __launch_bounds__(256) void pack_kernel(
    const float* __restrict__ Wih, const float* __restrict__ Whh,
    const float* __restrict__ Wout, const float* __restrict__ c0,
    const float* __restrict__ h0,
    half_t* __restrict__ wih_t, half_t* __restrict__ wout_t,
    unsigned int* __restrict__ whh_mf,
    float* __restrict__ state_c, unsigned int* __restrict__ state_h)
{
    const int stride = gridDim.x * blockDim.x;
    for (int idx = blockIdx.x * blockDim.x + threadIdx.x; idx < PACK_TOTAL; idx += stride) {
        int r = idx;
        if (r < 262144) {                       // wih_t[n][k] = Wih[k][n]
            int n = r >> 8, k = r & 255;
            wih_t[r] = (half_t)Wih[k * 1024 + n];
            continue;
        }
        r -= 262144;
        if (r < 65536) {                        // wout_t[n][k] = Wout[k][n]
            int n = r >> 8, k = r & 255;
            wout_t[r] = (half_t)Wout[k * 256 + n];
            continue;
        }
        r -= 65536;
        if (r < 131072) {                       // MFMA B-frags: frag[kt][nt][lane], 4 words each
            int j    = r & 3;                   // word within frag (k pair 2j,2j+1)
            int lane = (r >> 2) & 63;
            int nt   = (r >> 8) & 63;
            int kt   = r >> 14;
            int k0 = kt * 32 + ((lane >> 4) << 3) + 2 * j;
            int n  = nt * 16 + (lane & 15);
            whh_mf[r] = packh2(Whh[k0 * 1024 + n], Whh[(k0 + 1) * 1024 + n]);
            continue;
        }
        r -= 131072;
        if (r < 16384) { state_c[r] = c0[r]; continue; }
        r -= 16384;
        state_h[r] = packh2(h0[2 * r], h0[2 * r + 1]);
    }
}

// ---------------- K1/K3: f16 MFMA GEMM, 128x128 tile, K=256 ----------------
template<int AMODE, int CMODE>
__global__ __launch_bounds__(256) void gemm16(
    const void* __restrict__ Ap, const half_t* __restrict__ Bt,
    void* __restrict__ Cp, const float* __restrict__ bias, int chunk0)
{
    __shared__ half_t Als[128][40];
    __shared__ half_t Bls[128][40];
    const int tid  = threadIdx.x;
    const int lane = tid & 63, wid = tid >> 6;
    const int wr = wid >> 1, wc = wid & 1;
    const int m0 = blockIdx.x * 128, n0 = blockIdx.y * 128;

    f32x4 acc[4][4] = {};

    for (int kc = 0; kc < 8; ++kc) {
        __syncthreads();
        if (AMODE == 1) {
            const float* A = (const float*)Ap;
            #pragma unroll
            for (int i = 0; i < 4; ++i) {
                int l = tid + i * 256;
                int row = l >> 3, kq = l & 7;
                int m = m0 + row;
                int arow = ((m >> 9) << 11) + chunk0 + (m & 511);
                f32x4 v = *(const f32x4*)(A + (size_t)arow * 256 + kc * 32 + kq * 4);
                uint2 pk;
                pk.x = packh2(v.x, v.y);
                pk.y = packh2(v.z, v.w);
                *reinterpret_cast<uint2*>(&Als[row][kq * 4]) = pk;
            }
        } else {
            const half_t* A = (const half_t*)Ap;
            #pragma unroll
            for (int i = 0; i < 2; ++i) {
                int l = tid + i * 256;
                int row = l >> 2, ko = l & 3;
                half8_t v = *(const half8_t*)(A + (size_t)(m0 + row) * 256 + kc * 32 + ko * 8);
                *reinterpret_cast<half8_t*>(&Als[row][ko * 8]) = v;
            }
        }
        #pragma unroll
        for (int i = 0; i < 2; ++i) {
            int l = tid + i * 256;
            int row = l >> 2, ko = l & 3;
            half8_t v = *(const half8_t*)(Bt + (size_t)(n0 + row) * 256 + kc * 32 + ko * 8);
            *reinterpret_cast<half8_t*>(&Bls[row][ko * 8]) = v;
        }
        __syncthreads();

        half8_t af[4], bf[4];
        #pragma unroll
        for (int mi = 0; mi < 4; ++mi)
            af[mi] = *reinterpret_cast<const half8_t*>(&Als[wr * 64 + mi * 16 + (lane & 15)][(lane >> 4) * 8]);
        #pragma unroll
        for (int ni = 0; ni < 4; ++ni)
            bf[ni] = *reinterpret_cast<const half8_t*>(&Bls[wc * 64 + ni * 16 + (lane & 15)][(lane >> 4) * 8]);
        #pragma unroll
        for (int mi = 0; mi < 4; ++mi)
            #pragma unroll
            for (int ni = 0; ni < 4; ++ni)
                acc[mi][ni] = __builtin_amdgcn_mfma_f32_16x16x32_f16(af[mi], bf[ni], acc[mi][ni], 0, 0, 0);
    }

    #pragma unroll
    for (int mi = 0; mi < 4; ++mi) {
        #pragma unroll
        for (int ni = 0; ni < 4; ++ni) {
            #pragma unroll
            for (int reg = 0; reg < 4; ++reg) {
                int row = m0 + wr * 64 + mi * 16 + (lane >> 4) * 4 + reg;   // m
                int col = n0 + wc * 64 + ni * 16 + (lane & 15);             // n
                float v = acc[mi][ni][reg] + bias[col];
                if (CMODE == 0) {
                    ((half_t*)Cp)[(size_t)row * 1024 + ((col & 255) << 2) + (col >> 8)] = (half_t)v;
                } else {
                    int crow = ((row >> 9) << 11) + chunk0 + (row & 511);
                    ((float*)Cp)[(size_t)crow * 256 + col] = v;
                }
            }
        }
    }
}

// ---------------- K2: per-chain recurrent LSTM via MFMA (M=1) ----------------
// 64 blocks, 512 threads = 8 waves = 2 waves/SIMD (TLP restored vs r6).
// Wave w owns nt in {w, w+8, w+16, ..., w+56}: chain j<4 -> nt=w+16j (gate j of
// e1=16w+lane), chain 4+j -> nt=w+8+16j (gate j of e2=e1+128). So lane l<16
// holds all 4 gate pre-activations of e1 and e2 in its own cc[0] registers ->
// LSTM update fully in-register: no gbuf, ONE barrier per step (hbuf ping-pong).
// B-frags: kt0-3 resident (128 regs), kt4-5 LDS (128 KB), kt6-7 streamed (L2-hot)
// with depth-1 cluster prefetch so L2 latency hides under MFMAs.
#define NT(ch) (((ch) < 4) ? (w + 16 * (ch)) : (w + 8 + 16 * ((ch) - 4)))
#define MFMA16(va, vb, vc) __builtin_amdgcn_mfma_f32_16x16x32_f16((va), (vb), (vc), 0, 0, 0)

__global__
__attribute__((amdgpu_flat_work_group_size(512, 512), amdgpu_waves_per_eu(2, 2)))
void rnn_kernel(
    const uint4v* __restrict__ whh_mf,
    const half_t* __restrict__ xw,
    half_t* __restrict__ h_out,
    float* __restrict__ state_c,
    unsigned int* __restrict__ state_h)
{
    __shared__ uint4v lds_b[2 * 4096];        // B-frag planes kt4,5: 131072 B
    __shared__ unsigned int hbuf[2][128];     // ping-pong h (f16[256] each)

    const int t    = threadIdx.x;
    const int lane = t & 63;
    const int w    = t >> 6;                 // wave 0..7
    const int b    = blockIdx.x;

    for (int i = t; i < 8192; i += 512) lds_b[i] = whh_mf[4 * 4096 + i];
    if (t < 128) hbuf[0][t] = state_h[b * 128 + t];

    // resident B-frags: kt0-3, this wave's 8 chains
    const half8_t* mf8 = (const half8_t*)whh_mf;
    half8_t Bres[4][8];
    #pragma unroll
    for (int kt = 0; kt < 4; ++kt)
        #pragma unroll
        for (int ch = 0; ch < 8; ++ch)
            Bres[kt][ch] = mf8[((size_t)kt * 64 + NT(ch)) * 64 + lane];

    const bool upd = (lane < 16);
    const int e1 = w * 16 + (lane & 15);     // in [0,128); e2 = e1+128
    float c1 = 0.f, c2 = 0.f;
    if (upd) { c1 = state_c[b * 256 + e1]; c2 = state_c[b * 256 + e1 + 128]; }
    const half_t* xp  = xw + (size_t)b * T_CH * 1024 + e1 * 4;
    half_t* hop = h_out + (size_t)b * T_CH * 256 + e1;
    __syncthreads();

    int p = 0;
    #pragma unroll 1
    for (int step = 0; step < T_CH; ++step) {
        const half_t* hbh = (const half_t*)hbuf[p];

        uint2 xv1, xv2; xv1.x = xv1.y = xv2.x = xv2.y = 0;
        if (upd) { xv1 = *(const uint2*)xp; xv2 = *(const uint2*)(xp + 512); }

        // A-frags: row 0 = h (lanes with lane&15==0 carry k-chunks), rows 1-15 zero
        half8_t a[8];
        #pragma unroll
        for (int kt = 0; kt < 8; ++kt) {
            half8_t v = {};
            if ((lane & 15) == 0)
                v = *(const half8_t*)(hbh + kt * 32 + (lane >> 4) * 8);
            a[kt] = v;
        }

        // prologue stream prefetch: chains 0,1 (planes kt6, kt7)
        half8_t s6[8], s7[8];
        s6[0] = mf8[((size_t)6 * 64 + NT(0)) * 64 + lane];
        s7[0] = mf8[((size_t)7 * 64 + NT(0)) * 64 + lane];
        s6[1] = mf8[((size_t)6 * 64 + NT(1)) * 64 + lane];
        s7[1] = mf8[((size_t)7 * 64 + NT(1)) * 64 + lane];

        float g[8];

        #pragma unroll
        for (int c = 0; c < 4; ++c) {
            const int ch0 = 2 * c, ch1 = 2 * c + 1;
            if (c < 3) {   // depth-1 prefetch of next cluster's stream frags
                s6[ch0 + 2] = mf8[((size_t)6 * 64 + NT(ch0 + 2)) * 64 + lane];
                s7[ch0 + 2] = mf8[((size_t)7 * 64 + NT(ch0 + 2)) * 64 + lane];
                s6[ch1 + 2] = mf8[((size_t)6 * 64 + NT(ch1 + 2)) * 64 + lane];
                s7[ch1 + 2] = mf8[((size_t)7 * 64 + NT(ch1 + 2)) * 64 + lane];
            }
            {
                half8_t l4 = *(const half8_t*)&lds_b[(size_t)NT(ch0) * 64 + lane];
                half8_t l5 = *(const half8_t*)&lds_b[4096 + (size_t)NT(ch0) * 64 + lane];
                f32x4 cc = {};
                cc = MFMA16(a[0], Bres[0][ch0], cc);
                cc = MFMA16(a[1], Bres[1][ch0], cc);
                cc = MFMA16(a[2], Bres[2][ch0], cc);
                cc = MFMA16(a[3], Bres[3][ch0], cc);
                cc = MFMA16(a[4], l4, cc);
                cc = MFMA16(a[5], l5, cc);
                cc = MFMA16(a[6], s6[ch0], cc);
                cc = MFMA16(a[7], s7[ch0], cc);
                g[ch0] = cc[0];
            }
            {
                half8_t l4 = *(const half8_t*)&lds_b[(size_t)NT(ch1) * 64 + lane];
                half8_t l5 = *(const half8_t*)&lds_b[4096 + (size_t)NT(ch1) * 64 + lane];
                f32x4 cc = {};
                cc = MFMA16(a[0], Bres[0][ch1], cc);
                cc = MFMA16(a[1], Bres[1][ch1], cc);
                cc = MFMA16(a[2], Bres[2][ch1], cc);
                cc = MFMA16(a[3], Bres[3][ch1], cc);
                cc = MFMA16(a[4], l4, cc);
                cc = MFMA16(a[5], l5, cc);
                cc = MFMA16(a[6], s6[ch1], cc);
                cc = MFMA16(a[7], s7[ch1], cc);
                g[ch1] = cc[0];
            }
        }

        // in-register LSTM update (lanes 0-15 of each wave: elements e1 and e2)
        half_t h16_1 = (half_t)0.f, h16_2 = (half_t)0.f;
        if (upd) {
            half2_t x0 = __builtin_bit_cast(half2_t, xv1.x);
            half2_t x1 = __builtin_bit_cast(half2_t, xv1.y);
            float A0 = g[0] + (float)x0.x;
            float A1 = g[1] + (float)x0.y;
            float A2 = g[2] + (float)x1.x;
            float A3 = g[3] + (float)x1.y;
            float ig = sigm(A0), fg = sigm(A1), gg = tanh_(A2), og = sigm(A3);
            c1 = fg * c1 + ig * gg;
            h16_1 = (half_t)(og * tanh_(c1));

            half2_t y0 = __builtin_bit_cast(half2_t, xv2.x);
            half2_t y1 = __builtin_bit_cast(half2_t, xv2.y);
            A0 = g[4] + (float)y0.x;
            A1 = g[5] + (float)y0.y;
            A2 = g[6] + (float)y1.x;
            A3 = g[7] + (float)y1.y;
            ig = sigm(A0); fg = sigm(A1); gg = tanh_(A2); og = sigm(A3);
            c2 = fg * c2 + ig * gg;
            h16_2 = (half_t)(og * tanh_(c2));

            half_t* hb = (half_t*)hbuf[p ^ 1];
            hb[e1]       = h16_1;
            hb[e1 + 128] = h16_2;
        }
        xp += 1024;
        __syncthreads();   // hbuf[p^1] writes -> next step's reads (single barrier/step)

        // deferred global store: drains at NEXT step's barrier, off the critical path
        if (upd) { hop[0] = h16_1; hop[128] = h16_2; }
        hop += 256;
        p ^= 1;
    }

    if (upd) {
        state_c[b * 256 + e1]       = c1;
        state_c[b * 256 + e1 + 128] = c2;
    }
    if (t < 128) state_h[b * 128 + t] = hbuf[p][t];   // T_CH even -> final h in buf 0
}

// ---------------- launch ----------------
extern "C" void kernel_launch(void* const* d_in, const int* in_sizes, int n_in,
                              void* d_out, int out_size, void* d_ws, size_t ws_size,
                              hipStream_t stream) {
    const float* x    = (const float*)d_in[0];
    const float* c0   = (const float*)d_in[1];
    const float* h0   = (const float*)d_in[2];
    const float* Wih  = (const float*)d_in[3];
    const float* Whh  = (const float*)d_in[4];
    const float* bh   = (const float*)d_in[5];
    const float* Wout = (const float*)d_in[6];
    const float* bout = (const float*)d_in[7];

    char* ws = (char*)d_ws;
    half_t* xw             = (half_t*)(ws + OFF_XW);
    half_t* h_chunk        = (half_t*)(ws + OFF_H);
    half_t* wih_t          = (half_t*)(ws + OFF_WIH);
    half_t* wout_t         = (half_t*)(ws + OFF_WOUT);
    unsigned int* whh_mf   = (unsigned int*)(ws + OFF_WMF);
    float* state_c         = (float*)(ws + OFF_SC);
    unsigned int* state_h  = (unsigned int*)(ws + OFF_SH);

    pack_kernel<<<512, 256, 0, stream>>>(Wih, Whh, Wout, c0, h0,
                                         wih_t, wout_t, whh_mf,
                                         state_c, state_h);

    for (int ch = 0; ch < N_CHUNK; ++ch) {
        int chunk0 = ch * T_CH;
        gemm16<1, 0><<<dim3(CH_M / 128, G4 / 128), 256, 0, stream>>>(
            (const void*)x, wih_t, (void*)xw, bh, chunk0);
        rnn_kernel<<<B_SZ, 512, 0, stream>>>((const uint4v*)(ws + OFF_WMF),
                                             xw, h_chunk, state_c, state_h);
        gemm16<0, 1><<<dim3(CH_M / 128, H_SZ / 128), 256, 0, stream>>>(
            (const void*)h_chunk, wout_t, d_out, bout, chunk0);
    }
    (void)in_sizes; (void)n_in; (void)out_size; (void)ws_size;
}